// Round 8
// baseline (351.184 us; speedup 1.0000x reference)
//
#include <hip/hip_runtime.h>
#include <hip/hip_fp16.h>

#define LDIM 2048
#define DDIM 1024
#define NB 8

typedef __attribute__((ext_vector_type(8))) _Float16 f16x8;
typedef __attribute__((ext_vector_type(4))) float f32x4;

#define MFMA16(a, b, c) __builtin_amdgcn_mfma_f32_16x16x32_f16(a, b, c, 0, 0, 0)

typedef const __attribute__((address_space(1))) unsigned int* gas_t;
typedef __attribute__((address_space(3))) unsigned int* las_t;

__device__ __forceinline__ void gl16(const _Float16* g, _Float16* l) {
  __builtin_amdgcn_global_load_lds((gas_t)g, (las_t)l, 16, 0, 0);
}

__device__ __forceinline__ f16x8 splat8(_Float16 x) {
  return (f16x8){x, x, x, x, x, x, x, x};
}

// ---------------------------------------------------------------------------
// R3-proven GEMM core: C_tile(128x128) += A(128 rows, K-major, LDA) x B^T.
// Single-buffered LDS, BK=64, gload_lds w=16, pre-swizzled source (measured
// conflict-free). scaleA(af, kt, ks) hook applied to A-frags before MFMA.
// NOTE: LDS content at (row, chunk c) holds global k-chunk c ^ (row&7); the
// frag read offset cs2 compensates, so a frag's DATA k-chunk is (ks*4+g4).
// ---------------------------------------------------------------------------
template <int KT, int LDA, class F>
__device__ __forceinline__ void gemm_core(const _Float16* __restrict__ Arow0,
                                          const _Float16* __restrict__ Brow0,
                                          _Float16* sA, _Float16* sB,
                                          f32x4 (&acc)[4][4], int tid, F scaleA) {
  const int w = tid >> 6, lane = tid & 63;
  const int wm = w >> 1, wn = w & 1;
  const int l15 = lane & 15, g4 = lane >> 4;

  const int rb = tid >> 3;
  const int csw = (tid & 7) ^ (rb & 7);
  const _Float16* ga = Arow0 + (size_t)rb * LDA + csw * 8;
  const _Float16* gb = Brow0 + (size_t)rb * LDA + csw * 8;
  _Float16* da = sA + (w << 9);
  _Float16* db = sB + (w << 9);

  for (int kt = 0; kt < KT; ++kt) {
    const size_t ko = (size_t)kt * 64;
#pragma unroll
    for (int is = 0; is < 4; ++is) {
      gl16(ga + (size_t)(is * 32) * LDA + ko, da + is * 2048);
      gl16(gb + (size_t)(is * 32) * LDA + ko, db + is * 2048);
    }
    __syncthreads();
#pragma unroll
    for (int ks = 0; ks < 2; ++ks) {
      const int cs2 = (((ks << 2) + g4) ^ (l15 & 7)) << 3;
      f16x8 af[4], bf[4];
#pragma unroll
      for (int mr = 0; mr < 4; ++mr)
        af[mr] = *(const f16x8*)&sA[(wm * 64 + mr * 16 + l15) * 64 + cs2];
#pragma unroll
      for (int nr = 0; nr < 4; ++nr)
        bf[nr] = *(const f16x8*)&sB[(wn * 64 + nr * 16 + l15) * 64 + cs2];
      scaleA(af, kt, ks);
#pragma unroll
      for (int mr = 0; mr < 4; ++mr)
#pragma unroll
        for (int nr = 0; nr < 4; ++nr)
          acc[mr][nr] = MFMA16(af[mr], bf[nr], acc[mr][nr]);
    }
    __syncthreads();
  }
}

// ---------------------------------------------------------------------------
// k_prep: F (fp32 [2048][1024]) -> H (fp16 [2048][1024]) + HT (fp16 [1024][2048])
// ---------------------------------------------------------------------------
__global__ __launch_bounds__(256)
void k_prep(const float* __restrict__ F1, const float* __restrict__ F2,
            _Float16* __restrict__ H1, _Float16* __restrict__ H2,
            _Float16* __restrict__ H1T, _Float16* __restrict__ H2T) {
  __shared__ _Float16 sT[64][72];
  const int bid = blockIdx.x;
  const int inp = bid >> 12;
  const int rem = bid & 4095;
  const int b = rem >> 9, rt = (rem >> 4) & 31, ct = rem & 15;
  const int r0 = rt * 64, c0 = ct * 64;

  const float* F = (inp ? F2 : F1) + (size_t)b * LDIM * DDIM;
  _Float16* H = (inp ? H2 : H1) + (size_t)b * LDIM * DDIM;
  _Float16* HT = (inp ? H2T : H1T) + (size_t)b * DDIM * LDIM;

  const int t = threadIdx.x;
  const int row = t >> 2, seg = (t & 3) * 16;
  {
    const float* src = F + (size_t)(r0 + row) * DDIM + c0 + seg;
    float4 v0 = *(const float4*)(src), v1 = *(const float4*)(src + 4);
    float4 v2 = *(const float4*)(src + 8), v3 = *(const float4*)(src + 12);
    f16x8 ha, hb;
#pragma unroll
    for (int j = 0; j < 4; ++j) {
      ha[j] = (_Float16)((&v0.x)[j]); ha[4 + j] = (_Float16)((&v1.x)[j]);
      hb[j] = (_Float16)((&v2.x)[j]); hb[4 + j] = (_Float16)((&v3.x)[j]);
    }
    _Float16* dst = H + (size_t)(r0 + row) * DDIM + c0 + seg;
    *(f16x8*)dst = ha;
    *(f16x8*)(dst + 8) = hb;
#pragma unroll
    for (int j = 0; j < 8; ++j) { sT[seg + j][row] = ha[j]; sT[seg + 8 + j][row] = hb[j]; }
  }
  __syncthreads();
  {
    const int cloc = t >> 2, rseg = (t & 3) * 16;
    _Float16* dst = HT + (size_t)(c0 + cloc) * LDIM + r0 + rseg;
    *(uint4*)dst = *(const uint4*)&sT[cloc][rseg];
    *(uint4*)(dst + 8) = *(const uint4*)&sT[cloc][rseg + 8];
  }
}

// ---------------------------------------------------------------------------
// k_qk: S = H1 H2^T (128x128 tiles, K=1024). Epilogue: per-(row, 128-block)
// partial softmax stats + P_unnorm fp16 (+ optionally P_unnorm^T via in-LDS
// transpose reusing the GEMM tiles' LDS).
// ---------------------------------------------------------------------------
template <bool WPT>
__global__ __launch_bounds__(256, 2)
void k_qk(const _Float16* __restrict__ H1, const _Float16* __restrict__ H2,
          _Float16* __restrict__ P, _Float16* __restrict__ PT,
          float2* __restrict__ partials) {
  __shared__ _Float16 sAB[16384];
  __shared__ float sRedM[128][2];
  __shared__ float sRedS[128][2];
  __shared__ float sM[128];

  const int tid = threadIdx.x;
  const int lane = tid & 63;
  const int w = tid >> 6, wm = w >> 1, wn = w & 1;
  const int l15 = lane & 15, g4 = lane >> 4;

  const int nwg = gridDim.x;  // 2048
  const int orig = blockIdx.x;
  const int idx = (orig & 7) * (nwg >> 3) + (orig >> 3);
  const int b = idx >> 8;
  const int mt = (idx >> 4) & 15, nt = idx & 15;
  const int m0 = mt << 7, n0 = nt << 7;

  f32x4 acc[4][4];
#pragma unroll
  for (int i = 0; i < 4; ++i)
#pragma unroll
    for (int j = 0; j < 4; ++j) acc[i][j] = (f32x4){0.f, 0.f, 0.f, 0.f};

  gemm_core<16, 1024>(H1 + (size_t)b * LDIM * DDIM + (size_t)m0 * DDIM,
                      H2 + (size_t)b * LDIM * DDIM + (size_t)n0 * DDIM,
                      sAB, sAB + 8192, acc, tid, [](f16x8*, int, int) {});

  // row max over the tile's 128 cols
#pragma unroll
  for (int mr = 0; mr < 4; ++mr)
#pragma unroll
    for (int r = 0; r < 4; ++r) {
      float v = fmaxf(fmaxf(acc[mr][0][r], acc[mr][1][r]),
                      fmaxf(acc[mr][2][r], acc[mr][3][r]));
#pragma unroll
      for (int off = 1; off < 16; off <<= 1) v = fmaxf(v, __shfl_xor(v, off, 64));
      if (l15 == 0) sRedM[wm * 64 + mr * 16 + g4 * 4 + r][wn] = v;
    }
  __syncthreads();
  if (tid < 128) sM[tid] = fmaxf(sRedM[tid][0], sRedM[tid][1]);
  __syncthreads();

  _Float16* pOut = P + ((size_t)b << 22);
#pragma unroll
  for (int mr = 0; mr < 4; ++mr)
#pragma unroll
    for (int r = 0; r < 4; ++r) {
      const int rloc = wm * 64 + mr * 16 + g4 * 4 + r;
      const float m = sM[rloc];
      float s = 0.f;
#pragma unroll
      for (int nr = 0; nr < 4; ++nr) {
        float p = __expf(acc[mr][nr][r] - m);
        s += p;
        const _Float16 ph = (_Float16)p;
        pOut[(size_t)(m0 + rloc) * LDIM + n0 + wn * 64 + nr * 16 + l15] = ph;
        if constexpr (WPT) {
          const int ncol = wn * 64 + nr * 16 + l15;
          sAB[ncol * 128 + (rloc ^ ((l15 & 7) << 4))] = ph;
        }
      }
#pragma unroll
      for (int off = 1; off < 16; off <<= 1) s += __shfl_xor(s, off, 64);
      if (l15 == 0) sRedS[rloc][wn] = s;
    }
  __syncthreads();
  if (tid < 128) {
    const float l = sRedS[tid][0] + sRedS[tid][1];
    partials[((size_t)(b * 16 + nt) << 11) + m0 + tid] = make_float2(sM[tid], l);
  }
  if constexpr (WPT) {
    const int n_ = tid >> 1, mh = tid & 1;
    const int swz = (n_ & 7) << 4;
    _Float16* dst = PT + ((size_t)b << 22) + (size_t)(n0 + n_) * LDIM + m0 + mh * 64;
#pragma unroll
    for (int o = 0; o < 8; ++o)
      *(uint4*)(dst + o * 8) = *(const uint4*)&sAB[n_ * 128 + ((mh * 64 + o * 8) ^ swz)];
  }
}

// ---------------------------------------------------------------------------
// fallback transpose: PT[n][m] = P[m][n] (no rescale)
// ---------------------------------------------------------------------------
__global__ __launch_bounds__(256)
void k_pt(const _Float16* __restrict__ P, _Float16* __restrict__ PT) {
  __shared__ _Float16 sT[64][72];
  const int bid = blockIdx.x;
  const int b = bid >> 10, mt = (bid >> 5) & 31, nt = bid & 31;
  const int m0 = mt * 64, n0 = nt * 64;
  const _Float16* p = P + ((size_t)b << 22);
  _Float16* pt = PT + ((size_t)b << 22);
  const int t = threadIdx.x;
  const int row = t >> 2, seg = (t & 3) * 16;
  {
    const _Float16* src = p + (size_t)(m0 + row) * LDIM + n0 + seg;
    f16x8 h0 = *(const f16x8*)src, h1 = *(const f16x8*)(src + 8);
#pragma unroll
    for (int j = 0; j < 8; ++j) { sT[seg + j][row] = h0[j]; sT[seg + 8 + j][row] = h1[j]; }
  }
  __syncthreads();
  {
    const int nloc = t >> 2, mseg = (t & 3) * 16;
    _Float16* dst = pt + (size_t)(n0 + nloc) * LDIM + m0 + mseg;
    *(uint4*)dst = *(const uint4*)&sT[nloc][mseg];
    *(uint4*)(dst + 8) = *(const uint4*)&sT[nloc][mseg + 8];
  }
}

// ---------------------------------------------------------------------------
// k_merge: partials -> g (e^{mp-M}, fp32), h (e^{mp-M}/L, fp16), invL (fp32)
// ---------------------------------------------------------------------------
__global__ void k_merge(const float2* __restrict__ partials, float* __restrict__ g16,
                        _Float16* __restrict__ h16, float* __restrict__ invL) {
  const int t = blockIdx.x * 256 + threadIdx.x;
  if (t >= NB * LDIM) return;
  const int b = t >> 11, row = t & 2047;
  float2 p[16];
  float M = -1e30f;
#pragma unroll
  for (int i = 0; i < 16; ++i) {
    p[i] = partials[((size_t)(b * 16 + i) << 11) + row];
    M = fmaxf(M, p[i].x);
  }
  float L = 0.f;
#pragma unroll
  for (int i = 0; i < 16; ++i) L += p[i].y * __expf(p[i].x - M);
  const float inv = 1.0f / L;
  invL[((size_t)b << 11) + row] = inv;
#pragma unroll
  for (int i = 0; i < 16; ++i) {
    const float g = __expf(p[i].x - M);
    const size_t o = ((size_t)(b * 16 + i) << 11) + row;
    g16[o] = g;
    h16[o] = (_Float16)(g * inv);
  }
}

// ---------------------------------------------------------------------------
// k_att1: out1 = P_final @ F2.  A = P_u, B = H2T; fold g per (row, kblock) in
// the hot loop, 1/L in the epilogue.
// ---------------------------------------------------------------------------
__global__ __launch_bounds__(256, 2)
void k_att1(const _Float16* __restrict__ Pu, const _Float16* __restrict__ H2T,
            const float* __restrict__ g16, const float* __restrict__ invL,
            float* __restrict__ Out) {
  __shared__ _Float16 sA[8192];
  __shared__ _Float16 sB[8192];
  __shared__ float sG[16][128];
  __shared__ float sL[128];

  const int tid = threadIdx.x;
  const int lane = tid & 63;
  const int w = tid >> 6, wm = w >> 1, wn = w & 1;
  const int l15 = lane & 15, g4 = lane >> 4;

  const int nwg = gridDim.x;  // 1024
  const int orig = blockIdx.x;
  const int idx = (orig & 7) * (nwg >> 3) + (orig >> 3);
  const int b = idx >> 7, mt = (idx >> 3) & 15, dt = idx & 7;
  const int m0 = mt << 7, d0 = dt << 7;

#pragma unroll
  for (int i = 0; i < 8; ++i) {
    const int ix = i * 256 + tid;
    sG[ix >> 7][ix & 127] = g16[((size_t)(b * 16 + (ix >> 7)) << 11) + m0 + (ix & 127)];
  }
  if (tid < 128) sL[tid] = invL[((size_t)b << 11) + m0 + tid];
  __syncthreads();

  f32x4 acc[4][4];
#pragma unroll
  for (int i = 0; i < 4; ++i)
#pragma unroll
    for (int j = 0; j < 4; ++j) acc[i][j] = (f32x4){0.f, 0.f, 0.f, 0.f};

  _Float16 gh[4];
  auto scaleA = [&](f16x8* af, int kt, int ks) {
    if (ks == 0 && !(kt & 1)) {
      const int kb = kt >> 1;
#pragma unroll
      for (int mr = 0; mr < 4; ++mr)
        gh[mr] = (_Float16)sG[kb][wm * 64 + mr * 16 + l15];
    }
#pragma unroll
    for (int mr = 0; mr < 4; ++mr) af[mr] *= splat8(gh[mr]);
  };

  gemm_core<32, 2048>(Pu + ((size_t)b << 22) + (size_t)m0 * LDIM,
                      H2T + ((size_t)b << 21) + (size_t)d0 * LDIM,
                      sA, sB, acc, tid, scaleA);

  float* outp = Out + (size_t)b * LDIM * DDIM;
#pragma unroll
  for (int mr = 0; mr < 4; ++mr)
#pragma unroll
    for (int r = 0; r < 4; ++r) {
      const float sl = sL[wm * 64 + mr * 16 + g4 * 4 + r];
#pragma unroll
      for (int nr = 0; nr < 4; ++nr)
        outp[(size_t)(m0 + wm * 64 + mr * 16 + g4 * 4 + r) * DDIM +
             d0 + wn * 64 + nr * 16 + l15] = acc[mr][nr][r] * sl;
    }
}

// ---------------------------------------------------------------------------
// k_att2: out2 = P_final^T @ F1.  A = P_u^T, B = H1T; fold h (= g/L of the
// block's n-range) along K. FIX (R7 bug): index sH by the frag's DATA k-chunk
// ((ks*4+g4)*8), NOT the swizzled LDS offset cs2 — sH is stored linearly.
// ---------------------------------------------------------------------------
__global__ __launch_bounds__(256, 2)
void k_att2(const _Float16* __restrict__ PuT, const _Float16* __restrict__ H1T,
            const _Float16* __restrict__ h16, float* __restrict__ Out) {
  __shared__ _Float16 sA[8192];
  __shared__ _Float16 sB[8192];
  __shared__ _Float16 sH[2048];

  const int tid = threadIdx.x;
  const int lane = tid & 63;
  const int w = tid >> 6, wm = w >> 1, wn = w & 1;
  const int l15 = lane & 15, g4 = lane >> 4;

  const int nwg = gridDim.x;  // 1024
  const int orig = blockIdx.x;
  const int idx = (orig & 7) * (nwg >> 3) + (orig >> 3);
  const int b = idx >> 7, mt = (idx >> 3) & 15, dt = idx & 7;
  const int m0 = mt << 7, d0 = dt << 7;   // m0 = out2 n-tile base; nb = mt

  *(f16x8*)&sH[tid * 8] =
      *(const f16x8*)&h16[((size_t)(b * 16 + mt) << 11) + tid * 8];
  __syncthreads();

  f32x4 acc[4][4];
#pragma unroll
  for (int i = 0; i < 4; ++i)
#pragma unroll
    for (int j = 0; j < 4; ++j) acc[i][j] = (f32x4){0.f, 0.f, 0.f, 0.f};

  auto scaleA = [&](f16x8* af, int kt, int ks) {
    const int kc = ((ks << 2) + g4) << 3;  // unswizzled data k-offset
    const f16x8 hv = *(const f16x8*)&sH[kt * 64 + kc];
#pragma unroll
    for (int mr = 0; mr < 4; ++mr) af[mr] *= hv;
  };

  gemm_core<32, 2048>(PuT + ((size_t)b << 22) + (size_t)m0 * LDIM,
                      H1T + ((size_t)b << 21) + (size_t)d0 * LDIM,
                      sA, sB, acc, tid, scaleA);

  float* outp = Out + (size_t)b * LDIM * DDIM;
#pragma unroll
  for (int mr = 0; mr < 4; ++mr)
#pragma unroll
    for (int nr = 0; nr < 4; ++nr)
#pragma unroll
      for (int r = 0; r < 4; ++r)
        outp[(size_t)(m0 + wm * 64 + mr * 16 + g4 * 4 + r) * DDIM +
             d0 + wn * 64 + nr * 16 + l15] = acc[mr][nr][r];
}

// ---------------------------------------------------------------------------
extern "C" void kernel_launch(void* const* d_in, const int* in_sizes, int n_in,
                              void* d_out, int out_size, void* d_ws, size_t ws_size,
                              hipStream_t stream) {
  const float* f1 = (const float*)d_in[0];
  const float* f2 = (const float*)d_in[1];
  float* out1 = (float*)d_out;
  float* out2 = out1 + (size_t)NB * LDIM * DDIM;

  const size_t MB = 1048576ull;
  char* ws = (char*)d_ws;
  _Float16* H1T = (_Float16*)(ws);                    // 32 MB
  _Float16* H2T = (_Float16*)(ws + 32 * MB);          // 32 MB
  _Float16* P   = (_Float16*)(ws + 64 * MB);          // 64 MB
  _Float16* H1  = (_Float16*)(ws + 128 * MB);         // 32 MB (dead after k_qk)
  _Float16* H2  = (_Float16*)(ws + 160 * MB);         // 32 MB (dead after k_qk)
  float2* partials = (float2*)(ws + 192 * MB);        // 2 MB
  float* g16  = (float*)(ws + 194 * MB);              // 1 MB
  _Float16* h16 = (_Float16*)(ws + 195 * MB);         // 512 KB
  float* invL = (float*)(ws + 195 * MB + 524288);     // 64 KB

  const bool fastpt = ws_size >= 260 * MB;
  _Float16* PT = (_Float16*)(fastpt ? ws + 196 * MB : ws + 128 * MB);  // 64 MB

  k_prep<<<dim3(8192), dim3(256), 0, stream>>>(f1, f2, H1, H2, H1T, H2T);
  if (fastpt) {
    k_qk<true><<<dim3(2048), dim3(256), 0, stream>>>(H1, H2, P, PT, partials);
  } else {
    k_qk<false><<<dim3(2048), dim3(256), 0, stream>>>(H1, H2, P, PT, partials);
    k_pt<<<dim3(8192), dim3(256), 0, stream>>>(P, PT);
  }
  k_merge<<<dim3(64), dim3(256), 0, stream>>>(partials, g16, h16, invL);
  k_att1<<<dim3(1024), dim3(256), 0, stream>>>(P, H2T, g16, invL, out1);
  k_att2<<<dim3(1024), dim3(256), 0, stream>>>(PT, H1T, h16, out2);
}

// Round 9
// 284.695 us; speedup vs baseline: 1.2335x; 1.2335x over previous
//
#include <hip/hip_runtime.h>
#include <hip/hip_fp16.h>

#define LDIM 2048
#define DDIM 1024
#define NB 8

typedef __attribute__((ext_vector_type(8))) _Float16 f16x8;
typedef __attribute__((ext_vector_type(4))) float f32x4;

#define MFMA16(a, b, c) __builtin_amdgcn_mfma_f32_16x16x32_f16(a, b, c, 0, 0, 0)

typedef const __attribute__((address_space(1))) unsigned int* gas_t;
typedef __attribute__((address_space(3))) unsigned int* las_t;

__device__ __forceinline__ void gl16(const _Float16* g, _Float16* l) {
  __builtin_amdgcn_global_load_lds((gas_t)g, (las_t)l, 16, 0, 0);
}

// ---------------------------------------------------------------------------
// R3-proven GEMM core: C_tile(128x128) += A(128 rows, K-major, LDA) x B^T.
// Single-buffered LDS, BK=64, gload_lds w=16, pre-swizzled source (measured
// conflict-free, R3: SQ_LDS_BANK_CONFLICT = 0).
// ---------------------------------------------------------------------------
template <int KT, int LDA>
__device__ __forceinline__ void gemm_core(const _Float16* __restrict__ Arow0,
                                          const _Float16* __restrict__ Brow0,
                                          _Float16* sA, _Float16* sB,
                                          f32x4 (&acc)[4][4], int tid) {
  const int w = tid >> 6, lane = tid & 63;
  const int wm = w >> 1, wn = w & 1;
  const int l15 = lane & 15, g4 = lane >> 4;

  const int rb = tid >> 3;
  const int csw = (tid & 7) ^ (rb & 7);
  const _Float16* ga = Arow0 + (size_t)rb * LDA + csw * 8;
  const _Float16* gb = Brow0 + (size_t)rb * LDA + csw * 8;
  _Float16* da = sA + (w << 9);
  _Float16* db = sB + (w << 9);

  for (int kt = 0; kt < KT; ++kt) {
    const size_t ko = (size_t)kt * 64;
#pragma unroll
    for (int is = 0; is < 4; ++is) {
      gl16(ga + (size_t)(is * 32) * LDA + ko, da + is * 2048);
      gl16(gb + (size_t)(is * 32) * LDA + ko, db + is * 2048);
    }
    __syncthreads();
#pragma unroll
    for (int ks = 0; ks < 2; ++ks) {
      const int cs2 = (((ks << 2) + g4) ^ (l15 & 7)) << 3;
      f16x8 af[4], bf[4];
#pragma unroll
      for (int mr = 0; mr < 4; ++mr)
        af[mr] = *(const f16x8*)&sA[(wm * 64 + mr * 16 + l15) * 64 + cs2];
#pragma unroll
      for (int nr = 0; nr < 4; ++nr)
        bf[nr] = *(const f16x8*)&sB[(wn * 64 + nr * 16 + l15) * 64 + cs2];
#pragma unroll
      for (int mr = 0; mr < 4; ++mr)
#pragma unroll
        for (int nr = 0; nr < 4; ++nr)
          acc[mr][nr] = MFMA16(af[mr], bf[nr], acc[mr][nr]);
    }
    __syncthreads();
  }
}

// ---------------------------------------------------------------------------
// k_prep: F (fp32 [2048][1024]) -> H (fp16 [2048][1024]) + HT (fp16 [1024][2048])
// ---------------------------------------------------------------------------
__global__ __launch_bounds__(256)
void k_prep(const float* __restrict__ F1, const float* __restrict__ F2,
            _Float16* __restrict__ H1, _Float16* __restrict__ H2,
            _Float16* __restrict__ H1T, _Float16* __restrict__ H2T) {
  __shared__ _Float16 sT[64][72];
  const int bid = blockIdx.x;
  const int inp = bid >> 12;
  const int rem = bid & 4095;
  const int b = rem >> 9, rt = (rem >> 4) & 31, ct = rem & 15;
  const int r0 = rt * 64, c0 = ct * 64;

  const float* F = (inp ? F2 : F1) + (size_t)b * LDIM * DDIM;
  _Float16* H = (inp ? H2 : H1) + (size_t)b * LDIM * DDIM;
  _Float16* HT = (inp ? H2T : H1T) + (size_t)b * DDIM * LDIM;

  const int t = threadIdx.x;
  const int row = t >> 2, seg = (t & 3) * 16;
  {
    const float* src = F + (size_t)(r0 + row) * DDIM + c0 + seg;
    float4 v0 = *(const float4*)(src), v1 = *(const float4*)(src + 4);
    float4 v2 = *(const float4*)(src + 8), v3 = *(const float4*)(src + 12);
    f16x8 ha, hb;
#pragma unroll
    for (int j = 0; j < 4; ++j) {
      ha[j] = (_Float16)((&v0.x)[j]); ha[4 + j] = (_Float16)((&v1.x)[j]);
      hb[j] = (_Float16)((&v2.x)[j]); hb[4 + j] = (_Float16)((&v3.x)[j]);
    }
    _Float16* dst = H + (size_t)(r0 + row) * DDIM + c0 + seg;
    *(f16x8*)dst = ha;
    *(f16x8*)(dst + 8) = hb;
#pragma unroll
    for (int j = 0; j < 8; ++j) { sT[seg + j][row] = ha[j]; sT[seg + 8 + j][row] = hb[j]; }
  }
  __syncthreads();
  {
    const int cloc = t >> 2, rseg = (t & 3) * 16;
    _Float16* dst = HT + (size_t)(c0 + cloc) * LDIM + r0 + rseg;
    *(uint4*)dst = *(const uint4*)&sT[cloc][rseg];
    *(uint4*)(dst + 8) = *(const uint4*)&sT[cloc][rseg + 8];
  }
}

// ---------------------------------------------------------------------------
// k_qk: S = H1 H2^T (128x128 tiles, K=1024). Epilogue: per-(row, 128-block)
// partial softmax stats + P_unnorm fp16. Reduction scratch ALIASED into the
// (dead) GEMM tile LDS -> block uses exactly 32 KB -> 5 blocks/CU.
// ---------------------------------------------------------------------------
__global__ __launch_bounds__(256, 2)
void k_qk(const _Float16* __restrict__ H1, const _Float16* __restrict__ H2,
          _Float16* __restrict__ P, float2* __restrict__ partials) {
  __shared__ _Float16 sAB[16384];   // 32 KB: sA = [0,8192), sB = [8192,16384)

  const int tid = threadIdx.x;
  const int lane = tid & 63;
  const int w = tid >> 6, wm = w >> 1, wn = w & 1;
  const int l15 = lane & 15, g4 = lane >> 4;

  const int nwg = gridDim.x;  // 2048
  const int orig = blockIdx.x;
  const int idx = (orig & 7) * (nwg >> 3) + (orig >> 3);
  const int b = idx >> 8;
  const int mt = (idx >> 4) & 15, nt = idx & 15;
  const int m0 = mt << 7, n0 = nt << 7;

  f32x4 acc[4][4];
#pragma unroll
  for (int i = 0; i < 4; ++i)
#pragma unroll
    for (int j = 0; j < 4; ++j) acc[i][j] = (f32x4){0.f, 0.f, 0.f, 0.f};

  gemm_core<16, 1024>(H1 + (size_t)b * LDIM * DDIM + (size_t)m0 * DDIM,
                      H2 + (size_t)b * LDIM * DDIM + (size_t)n0 * DDIM,
                      sAB, sAB + 8192, acc, tid);

  // epilogue scratch aliased into sAB (GEMM tiles dead after the last sync)
  float* sRedM = (float*)sAB;            // [128][2]
  float* sRedS = sRedM + 256;            // [128][2]
  float* sM = sRedS + 256;               // [128]

  // row max over the tile's 128 cols
#pragma unroll
  for (int mr = 0; mr < 4; ++mr)
#pragma unroll
    for (int r = 0; r < 4; ++r) {
      float v = fmaxf(fmaxf(acc[mr][0][r], acc[mr][1][r]),
                      fmaxf(acc[mr][2][r], acc[mr][3][r]));
#pragma unroll
      for (int off = 1; off < 16; off <<= 1) v = fmaxf(v, __shfl_xor(v, off, 64));
      if (l15 == 0) sRedM[(wm * 64 + mr * 16 + g4 * 4 + r) * 2 + wn] = v;
    }
  __syncthreads();
  if (tid < 128) sM[tid] = fmaxf(sRedM[tid * 2], sRedM[tid * 2 + 1]);
  __syncthreads();

  _Float16* pOut = P + ((size_t)b << 22);
#pragma unroll
  for (int mr = 0; mr < 4; ++mr)
#pragma unroll
    for (int r = 0; r < 4; ++r) {
      const int rloc = wm * 64 + mr * 16 + g4 * 4 + r;
      const float m = sM[rloc];
      float s = 0.f;
#pragma unroll
      for (int nr = 0; nr < 4; ++nr) {
        float p = __expf(acc[mr][nr][r] - m);
        s += p;
        pOut[(size_t)(m0 + rloc) * LDIM + n0 + wn * 64 + nr * 16 + l15] = (_Float16)p;
      }
#pragma unroll
      for (int off = 1; off < 16; off <<= 1) s += __shfl_xor(s, off, 64);
      if (l15 == 0) sRedS[rloc * 2 + wn] = s;
    }
  __syncthreads();
  if (tid < 128) {
    const float l = sRedS[tid * 2] + sRedS[tid * 2 + 1];
    partials[((size_t)(b * 16 + nt) << 11) + m0 + tid] = make_float2(sM[tid], l);
  }
}

// ---------------------------------------------------------------------------
// k_merge: partial stats -> per-(row, n-block) rescale factors e^(m_p - M) / L
// ---------------------------------------------------------------------------
__global__ void k_merge(const float2* __restrict__ partials, float* __restrict__ factors) {
  const int t = blockIdx.x * 256 + threadIdx.x;
  if (t >= NB * LDIM) return;
  const int b = t >> 11, row = t & 2047;
  float2 p[16];
  float M = -1e30f;
#pragma unroll
  for (int i = 0; i < 16; ++i) {
    p[i] = partials[((size_t)(b * 16 + i) << 11) + row];
    M = fmaxf(M, p[i].x);
  }
  float L = 0.f;
#pragma unroll
  for (int i = 0; i < 16; ++i) L += p[i].y * __expf(p[i].x - M);
  const float inv = 1.0f / L;
#pragma unroll
  for (int i = 0; i < 16; ++i)
    factors[((size_t)(b * 16 + i) << 11) + row] = __expf(p[i].x - M) * inv;
}

// ---------------------------------------------------------------------------
// k_scale_t: P[m][n] *= f[m][n>>7] in place; also write PT[n][m] (rescaled).
// ---------------------------------------------------------------------------
__global__ __launch_bounds__(256)
void k_scale_t(_Float16* __restrict__ P, const float* __restrict__ factors,
               _Float16* __restrict__ PT) {
  __shared__ _Float16 sT[64][72];
  const int bid = blockIdx.x;
  const int b = bid >> 10, mt = (bid >> 5) & 31, nt = bid & 31;
  const int m0 = mt * 64, n0 = nt * 64;
  const int nblk = n0 >> 7;

  _Float16* p = P + ((size_t)b << 22);
  _Float16* pt = PT + ((size_t)b << 22);

  const int t = threadIdx.x;
  const int row = t >> 2, seg = (t & 3) * 16;
  {
    const float f = factors[((size_t)(b * 16 + nblk) << 11) + m0 + row];
    const _Float16 hf = (_Float16)f;
    _Float16* src = p + (size_t)(m0 + row) * LDIM + n0 + seg;
    f16x8 h0 = *(const f16x8*)src, h1 = *(const f16x8*)(src + 8);
#pragma unroll
    for (int j = 0; j < 8; ++j) { h0[j] *= hf; h1[j] *= hf; }
    *(f16x8*)src = h0;
    *(f16x8*)(src + 8) = h1;
#pragma unroll
    for (int j = 0; j < 8; ++j) { sT[seg + j][row] = h0[j]; sT[seg + 8 + j][row] = h1[j]; }
  }
  __syncthreads();
  {
    const int nloc = t >> 2, mseg = (t & 3) * 16;
    _Float16* dst = pt + (size_t)(n0 + nloc) * LDIM + m0 + mseg;
    *(uint4*)dst = *(const uint4*)&sT[nloc][mseg];
    *(uint4*)(dst + 8) = *(const uint4*)&sT[nloc][mseg + 8];
  }
}

// ---------------------------------------------------------------------------
// k_gemm: C[2048][1024] = A(2048 rows, K=2048) x B(1024 rows, K=2048)^T
// ---------------------------------------------------------------------------
__global__ __launch_bounds__(256, 2)
void k_gemm(const _Float16* __restrict__ A, const _Float16* __restrict__ B,
            float* __restrict__ C) {
  __shared__ _Float16 sA[8192];
  __shared__ _Float16 sB[8192];

  const int tid = threadIdx.x;
  const int lane = tid & 63;
  const int w = tid >> 6, wm = w >> 1, wn = w & 1;
  const int l15 = lane & 15, g4 = lane >> 4;

  const int nwg = gridDim.x;  // 1024
  const int orig = blockIdx.x;
  const int idx = (orig & 7) * (nwg >> 3) + (orig >> 3);
  const int b = idx >> 7;
  const int mt = (idx >> 3) & 15, nt = idx & 7;
  const int m0 = mt << 7, d0 = nt << 7;

  f32x4 acc[4][4];
#pragma unroll
  for (int i = 0; i < 4; ++i)
#pragma unroll
    for (int j = 0; j < 4; ++j) acc[i][j] = (f32x4){0.f, 0.f, 0.f, 0.f};

  gemm_core<32, 2048>(A + ((size_t)b << 22) + (size_t)m0 * LDIM,
                      B + ((size_t)b << 21) + (size_t)d0 * LDIM,
                      sA, sB, acc, tid);

  float* outp = C + (size_t)b * LDIM * DDIM;
#pragma unroll
  for (int mr = 0; mr < 4; ++mr)
#pragma unroll
    for (int nr = 0; nr < 4; ++nr)
#pragma unroll
      for (int r = 0; r < 4; ++r)
        outp[(size_t)(m0 + wm * 64 + mr * 16 + g4 * 4 + r) * DDIM +
             d0 + wn * 64 + nr * 16 + l15] = acc[mr][nr][r];
}

// ---------------------------------------------------------------------------
extern "C" void kernel_launch(void* const* d_in, const int* in_sizes, int n_in,
                              void* d_out, int out_size, void* d_ws, size_t ws_size,
                              hipStream_t stream) {
  const float* f1 = (const float*)d_in[0];
  const float* f2 = (const float*)d_in[1];
  float* out1 = (float*)d_out;
  float* out2 = out1 + (size_t)NB * LDIM * DDIM;

  char* ws = (char*)d_ws;
  _Float16* H1T = (_Float16*)(ws);                         // 32 MB
  _Float16* H2T = (_Float16*)(ws + 33554432ull);           // 32 MB
  _Float16* P   = (_Float16*)(ws + 67108864ull);           // 64 MB
  _Float16* PT  = (_Float16*)(ws + 134217728ull);          // 64 MB (overlaps H1,H2)
  _Float16* H1  = (_Float16*)(ws + 134217728ull);          // 32 MB (dead after k_qk)
  _Float16* H2  = (_Float16*)(ws + 167772160ull);          // 32 MB (dead after k_qk)
  float2* partials = (float2*)(ws + 201326592ull);         // 2 MB
  float* factors   = (float*)(ws + 203423744ull);          // 1 MB

  k_prep<<<dim3(8192), dim3(256), 0, stream>>>(f1, f2, H1, H2, H1T, H2T);
  k_qk<<<dim3(2048), dim3(256), 0, stream>>>(H1, H2, P, partials);
  k_merge<<<dim3(64), dim3(256), 0, stream>>>(partials, factors);
  k_scale_t<<<dim3(8192), dim3(256), 0, stream>>>(P, factors, PT);
  k_gemm<<<dim3(1024), dim3(256), 0, stream>>>(P, H2T, out1);
  k_gemm<<<dim3(1024), dim3(256), 0, stream>>>(PT, H1T, out2);
}